// Round 11
// baseline (231.922 us; speedup 1.0000x reference)
//
#include <hip/hip_runtime.h>

typedef __bf16 bf16;
typedef __bf16 bf16x4 __attribute__((ext_vector_type(4)));
typedef __bf16 bf16x8 __attribute__((ext_vector_type(8)));
typedef float f32x4 __attribute__((ext_vector_type(4)));
typedef float f32x16 __attribute__((ext_vector_type(16)));

#define T_ 4
#define B_ 8
#define C_ 512
#define D_ 768
#define H_ 8
#define HL_ 2
#define HD_ 96
#define MKV_ 192
#define M2_ 4096            // B*C
#define BCD_ 3145728        // B*C*D
#define M3_ 16384           // T*B*C
#define NCOMB 1152          // q(768) + k(192) + v(192)
#define SUSP_CAP 65536
#define SUSP_WIN 2e-4f

// async global->LDS, 16B per lane (dest = wave-uniform base + lane*16; no pad)
__device__ __forceinline__ void gld16(const bf16* g, bf16* l) {
    __builtin_amdgcn_global_load_lds(
        (const __attribute__((address_space(1))) unsigned int*)g,
        (__attribute__((address_space(3))) unsigned int*)l, 16, 0, 0);
}

// all waves finished reading the LDS buffer we are about to overwrite
#define READS_DONE() do {                                                     \
    asm volatile("s_waitcnt lgkmcnt(0)" ::: "memory");                        \
    __builtin_amdgcn_s_barrier();                                             \
    __builtin_amdgcn_sched_barrier(0);                                        \
} while (0)

// counted wait: next buffer's loads (issued a full iter ago) have landed;
// the just-issued ones stay in flight
#define NEXT_READY(N) do {                                                    \
    asm volatile("s_waitcnt vmcnt(" #N ")" ::: "memory");                     \
    __builtin_amdgcn_s_barrier();                                             \
} while (0)

// ---------------------------------------------------------------------------
// Kernel 1: fused prep — VECTORIZED. xs=lif(x) fp64 scan (8/thread,
// float4 loads + bf16x8 stores), q/k/v hi/lo split, wo cvt, susp reset.
// ---------------------------------------------------------------------------
__global__ __launch_bounds__(256) void prep_kernel(
    const float* __restrict__ x, const float* __restrict__ q_w,
    const float* __restrict__ k_w, const float* __restrict__ v_w,
    const float* __restrict__ wo_w, bf16* __restrict__ xs,
    bf16* __restrict__ whi, bf16* __restrict__ wlo, bf16* __restrict__ wo_bf,
    unsigned* __restrict__ susp)
{
    const int t0 = blockIdx.x * 256 + threadIdx.x;
    const int stride = gridDim.x * 256;
    if (t0 == 0) susp[0] = 0;
    for (int i = t0 * 8; i < BCD_; i += stride * 8) {
        double v[8] = {0.0, 0.0, 0.0, 0.0, 0.0, 0.0, 0.0, 0.0};
        #pragma unroll
        for (int t = 0; t < T_; ++t) {
            const float* xp = x + (size_t)t * BCD_ + i;
            f32x4 xa = *(const f32x4*)xp;
            f32x4 xb = *(const f32x4*)(xp + 4);
            bf16x8 s;
            #pragma unroll
            for (int e = 0; e < 8; ++e) {
                float xe = (e < 4) ? xa[e] : xb[e - 4];
                v[e] = v[e] * 0.5 + (double)xe;
                float sp = (v[e] >= 1.0) ? 1.f : 0.f;
                s[e] = (bf16)sp;
                v[e] *= (double)(1.f - sp);     // exact: *0 or *1
            }
            *(bf16x8*)(xs + (size_t)t * BCD_ + i) = s;
        }
    }
    for (int i = t0 * 4; i < NCOMB * D_; i += stride * 4) {
        int row = i / D_, col = i - row * D_;
        const float* src;
        if (row < 768)      src = q_w + (size_t)row * D_ + col;
        else if (row < 960) src = k_w + (size_t)(row - 768) * D_ + col;
        else                src = v_w + (size_t)(row - 960) * D_ + col;
        f32x4 wv = *(const f32x4*)src;
        bf16x4 hh, ll;
        #pragma unroll
        for (int e = 0; e < 4; ++e) {
            bf16 h = (bf16)wv[e];
            hh[e] = h;
            ll[e] = (bf16)(wv[e] - (float)h);
        }
        *(bf16x4*)(whi + i) = hh;
        *(bf16x4*)(wlo + i) = ll;
    }
    for (int i = t0 * 4; i < D_ * D_; i += stride * 4) {
        f32x4 wv = *(const f32x4*)(wo_w + i);
        bf16x4 c;
        #pragma unroll
        for (int e = 0; e < 4; ++e) c[e] = (bf16)wv[e];
        *(bf16x4*)(wo_bf + i) = c;
    }
}

// ---------------------------------------------------------------------------
// Kernel 2: combined spiking projection. r10 schedule EXACT (64x64 block,
// BK=32, named dbuf 48KB, counted-vmcnt full-iteration prefetch, 4-slot XOR
// swizzle, XCD swizzle) — but MFMA shape switched 16x16x32 -> 32x32x16:
// HALF the MFMA issues per step (16 vs 32) at better FLOP/cyc (2382 vs 2075
// TF ubench), identical LDS/staging schedule. Wave tile still 32m x 32n.
// A: row=lane&31, k-octet=lane>>5 (gfx950 2xK lane rule, mirrors verified
// 16x16x32 quad=lane>>4). C/D: col=lane&31, row=(reg&3)+8*(reg>>2)+
// 4*(lane>>5) [HW-verified m74/m101].
// ---------------------------------------------------------------------------
__global__ __launch_bounds__(256, 3) void proj_lif_kernel(
    const bf16* __restrict__ xs, const bf16* __restrict__ Whi,
    const bf16* __restrict__ Wlo,
    bf16* __restrict__ q_sp, bf16* __restrict__ k_sp, bf16* __restrict__ v_sp,
    unsigned* __restrict__ susp)
{
    __shared__ __align__(16) bf16 A0[T_][64 * 32];   // 16 KB
    __shared__ __align__(16) bf16 A1[T_][64 * 32];   // 16 KB
    __shared__ __align__(16) bf16 H0[64 * 32];       //  4 KB
    __shared__ __align__(16) bf16 H1[64 * 32];       //  4 KB
    __shared__ __align__(16) bf16 L0[64 * 32];       //  4 KB
    __shared__ __align__(16) bf16 L1[64 * 32];       //  4 KB  (48 KB total)

    const int tid  = threadIdx.x;
    const int wave = tid >> 6, lane = tid & 63;
    const int l31  = lane & 31, lo8 = lane >> 5;
    const int wm   = wave >> 1, wn = wave & 1;

    // bijective XCD swizzle: xcd = bid&7 gets m-tiles [xcd*8, xcd*8+8) x all n
    const int bid   = blockIdx.y * 64 + blockIdx.x;   // grid (64, 18)
    const int xcd   = bid & 7;
    const int local = bid >> 3;                        // 0..143
    const int m0    = ((xcd << 3) | (local & 7)) * 64; // over M2
    const int n0    = (local >> 3) * 64;               // over NCOMB

    // output section for this wave's 32 columns
    const int colb = n0 + wn * 32;
    bf16* outp; int Nloc, cb;
    if (colb < 768)      { outp = q_sp; Nloc = 768; cb = colb; }
    else if (colb < 960) { outp = k_sp; Nloc = 192; cb = colb - 768; }
    else                 { outp = v_sp; Nloc = 192; cb = colb - 960; }

    f32x16 acc[T_];
    #pragma unroll
    for (int t = 0; t < T_; t++)
        #pragma unroll
        for (int e = 0; e < 16; e++) acc[t][e] = 0.f;

    // staging geometry: chunk = tid -> row = tid>>2, slot = tid&3,
    // source seg = slot ^ ((row>>1)&3)  (inverse swizzle on global src)
    const int srow = tid >> 2;
    const int sseg = (tid & 3) ^ ((tid >> 3) & 3);

#define STAGE(Ab, Hb, Lb, k0) do {                                            \
    _Pragma("unroll")                                                         \
    for (int t = 0; t < T_; t++)                                              \
        gld16(xs + (size_t)(t * M2_ + m0 + srow) * D_ + (k0) + sseg * 8,      \
              &Ab[t][tid * 8]);                                               \
    gld16(Whi + (size_t)(n0 + srow) * D_ + (k0) + sseg * 8, &Hb[tid * 8]);    \
    gld16(Wlo + (size_t)(n0 + srow) * D_ + (k0) + sseg * 8, &Lb[tid * 8]);    \
} while (0)

    bf16x8 a[T_][2], bh[2], bl[2];
    const int arow = wm * 32 + l31;      // A source row in LDS tile
    const int brow = wn * 32 + l31;      // B source row in LDS tile

#define LOADREGS(Ab, Hb, Lb) do {                                             \
    _Pragma("unroll")                                                         \
    for (int kh = 0; kh < 2; kh++) {                                          \
        int aoff = arow * 32 + ((((kh << 1) | lo8) ^ ((arow >> 1) & 3)) * 8); \
        int boff = brow * 32 + ((((kh << 1) | lo8) ^ ((brow >> 1) & 3)) * 8); \
        _Pragma("unroll")                                                     \
        for (int t = 0; t < T_; t++) a[t][kh] = *(const bf16x8*)&Ab[t][aoff]; \
        bh[kh] = *(const bf16x8*)&Hb[boff];                                   \
        bl[kh] = *(const bf16x8*)&Lb[boff];                                   \
    }                                                                         \
} while (0)

#define DOMFMA() do {                                                         \
    __builtin_amdgcn_s_setprio(1);                                            \
    _Pragma("unroll")                                                         \
    for (int kh = 0; kh < 2; kh++)                                            \
        _Pragma("unroll")                                                     \
        for (int t = 0; t < T_; t++) {                                        \
            acc[t] = __builtin_amdgcn_mfma_f32_32x32x16_bf16(                 \
                a[t][kh], bh[kh], acc[t], 0, 0, 0);                           \
            acc[t] = __builtin_amdgcn_mfma_f32_32x32x16_bf16(                 \
                a[t][kh], bl[kh], acc[t], 0, 0, 0);                           \
        }                                                                     \
    __builtin_amdgcn_s_setprio(0);                                            \
} while (0)

    STAGE(A0, H0, L0, 0);
    STAGE(A1, H1, L1, 32);
    NEXT_READY(6);                       // buf0 ready, buf1 in flight

    for (int s = 0; s < 22; s += 2) {    // iters u = s (buf0), u = s+1 (buf1)
        LOADREGS(A0, H0, L0);
        READS_DONE();
        STAGE(A0, H0, L0, (s + 2) * 32);
        DOMFMA();
        NEXT_READY(6);                   // buf1 (tile s+1) ready

        LOADREGS(A1, H1, L1);
        READS_DONE();
        STAGE(A1, H1, L1, (s + 3) * 32);
        DOMFMA();
        NEXT_READY(6);                   // buf0 (tile s+2) ready
    }
    // iter 22 (buf0): no more staging
    LOADREGS(A0, H0, L0);
    READS_DONE();
    DOMFMA();
    NEXT_READY(0);                       // buf1 (tile 23) ready
    // iter 23 (buf1)
    LOADREGS(A1, H1, L1);
    DOMFMA();

#undef STAGE
#undef LOADREGS
#undef DOMFMA

    // LIF scan over t (registers only) + spike stores + suspect flags.
    // C/D map: col = cb + l31, row = (reg&3) + 8*(reg>>2) + 4*lo8.
    #pragma unroll
    for (int reg = 0; reg < 16; reg++) {
        int row = m0 + wm * 32 + (reg & 3) + 8 * (reg >> 2) + 4 * lo8;
        int lc  = cb + l31;
        float v = 0.f;
        bool suspect = false;
        #pragma unroll
        for (int t = 0; t < T_; t++) {
            v = v * 0.5f + acc[t][reg];
            float d = v - 1.0f;
            if (fabsf(d) < SUSP_WIN) suspect = true;
            float sp = (d >= 0.f) ? 1.f : 0.f;
            v *= (1.f - sp);
            outp[(size_t)(t * M2_ + row) * Nloc + lc] = (bf16)sp;
        }
        if (suspect) {
            int ccol = colb + l31;
            unsigned idx = atomicAdd(susp, 1u);
            if (idx < SUSP_CAP) susp[1 + idx] = (unsigned)(row * 2048 + ccol);
        }
    }
}

// ---------------------------------------------------------------------------
// Kernel 2b: fp64 fixup, LATENCY-FLAT: prefetch the full W row (12 f32/lane)
// and all 4 xs rows (48 bf16/lane) as independent loads -> ONE memory wait
// -> 4 in-register dots + shuffle reduce + scan. Grid 1024.
// ---------------------------------------------------------------------------
__global__ __launch_bounds__(256) void fixup_kernel(
    const bf16* __restrict__ xs, const float* __restrict__ q_w,
    const float* __restrict__ k_w, const float* __restrict__ v_w,
    bf16* __restrict__ q_sp, bf16* __restrict__ k_sp, bf16* __restrict__ v_sp,
    const unsigned* __restrict__ susp)
{
    unsigned count = susp[0];
    if (count > SUSP_CAP) count = SUSP_CAP;
    const int lane = threadIdx.x & 63;
    const int wid  = (blockIdx.x * blockDim.x + threadIdx.x) >> 6;
    const int nw   = (gridDim.x * blockDim.x) >> 6;
    for (unsigned i = wid; i < count; i += nw) {
        unsigned e = susp[1 + i];
        int row = e >> 11, col = e & 2047;
        const float* W; bf16* outp; int Nloc, lc;
        if (col < 768)      { W = q_w + (size_t)col * D_;         outp = q_sp; Nloc = 768; lc = col; }
        else if (col < 960) { W = k_w + (size_t)(col - 768) * D_; outp = k_sp; Nloc = 192; lc = col - 768; }
        else                { W = v_w + (size_t)(col - 960) * D_; outp = v_sp; Nloc = 192; lc = col - 960; }
        float w[12];
        #pragma unroll
        for (int j = 0; j < 12; ++j) w[j] = W[lane + j * 64];
        float av[T_][12];
        #pragma unroll
        for (int t = 0; t < T_; ++t) {
            const bf16* ar = xs + (size_t)(t * M2_ + row) * D_;
            #pragma unroll
            for (int j = 0; j < 12; ++j) av[t][j] = (float)ar[lane + j * 64];
        }
        double v = 0.0;
        #pragma unroll
        for (int t = 0; t < T_; ++t) {
            double y = 0.0;
            #pragma unroll
            for (int j = 0; j < 12; ++j)
                y += (double)av[t][j] * (double)w[j];
            #pragma unroll
            for (int off = 1; off < 64; off <<= 1)
                y += __shfl_xor(y, off);
            v = v * 0.5 + y;
            unsigned sp = (v >= 1.0) ? 1u : 0u;
            if (lane == 0) outp[(size_t)(t * M2_ + row) * Nloc + lc] = (bf16)(float)sp;
            if (sp) v = 0.0;
        }
    }
}

// ---------------------------------------------------------------------------
// Kernel 3: partial k^T v. Block (g, cc): c-range cc*128..+128 (4 slices ->
// 256 blocks). Vectorized bf16x8 global loads, scalar LDS transpose
// scatter. fp32 exact integer partials -> M_part[cc][g][96][96].
// ---------------------------------------------------------------------------
__global__ __launch_bounds__(256) void ktv_kernel(
    const bf16* __restrict__ k_sp, const bf16* __restrict__ v_sp,
    float* __restrict__ M_part)
{
    const int g    = blockIdx.x;
    const int cc   = blockIdx.y;
    const int kvh  = g % HL_;
    const int tb   = g / HL_;
    const int wave = threadIdx.x >> 6;
    const int lane = threadIdx.x & 63;
    const int m16  = lane & 15, quad = lane >> 4;

    __shared__ __align__(16) bf16 klds[96 * 40];
    __shared__ __align__(16) bf16 vlds[96 * 40];

    f32x4 acc[9];
    #pragma unroll
    for (int i = 0; i < 9; i++) { f32x4 z = {0.f,0.f,0.f,0.f}; acc[i] = z; }

    const bf16* kbase = k_sp + ((size_t)tb * C_ + cc * 128) * MKV_ + kvh * HD_;
    const bf16* vbase = v_sp + ((size_t)tb * C_ + cc * 128) * MKV_ + kvh * HD_;

    for (int c0 = 0; c0 < 128; c0 += 32) {
        __syncthreads();
        // 32c x 12segs x 2 arrays = 768 bf16x8 chunks, 3 per thread
        for (int ci = threadIdx.x; ci < 768; ci += 256) {
            int arr = ci & 1;
            int pos = ci >> 1;
            int c = pos / 12, seg = pos - c * 12;
            const bf16* src = (arr ? vbase : kbase) + (size_t)(c0 + c) * MKV_ + seg * 8;
            bf16x8 val = *(const bf16x8*)src;
            bf16* dst = arr ? vlds : klds;
            #pragma unroll
            for (int e = 0; e < 8; e++)
                dst[(seg * 8 + e) * 40 + c] = val[e];
        }
        __syncthreads();
        #pragma unroll
        for (int i = 0; i < 9; i++) {
            int tile = wave + i * 4;
            int mt = tile / 6, nt = tile % 6;
            bf16x8 a = *(const bf16x8*)(&klds[(mt * 16 + m16) * 40 + quad * 8]);
            bf16x8 b = *(const bf16x8*)(&vlds[(nt * 16 + m16) * 40 + quad * 8]);
            acc[i] = __builtin_amdgcn_mfma_f32_16x16x32_bf16(a, b, acc[i], 0, 0, 0);
        }
    }
    float* op = M_part + ((size_t)cc * 64 + g) * HD_ * HD_;
    #pragma unroll
    for (int i = 0; i < 9; i++) {
        int tile = wave + i * 4;
        int mt = tile / 6, nt = tile % 6;
        #pragma unroll
        for (int r = 0; r < 4; r++) {
            int d = mt * 16 + quad * 4 + r;
            int j = nt * 16 + m16;
            op[(size_t)j * HD_ + d] = acc[i][r];
        }
    }
}

// ---------------------------------------------------------------------------
// Kernel 3b: sum 4 partials, split to exact hi/lo bf16.
// ---------------------------------------------------------------------------
__global__ __launch_bounds__(256) void cvtM_kernel(
    const float* __restrict__ M_part, bf16* __restrict__ M_hi,
    bf16* __restrict__ M_lo)
{
    int i = blockIdx.x * 256 + threadIdx.x;
    if (i >= 64 * HD_ * HD_) return;
    float m = 0.f;
    #pragma unroll
    for (int j = 0; j < 4; j++)
        m += M_part[i + (size_t)j * 589824];
    bf16 h = (bf16)m;
    M_hi[i] = h;
    M_lo[i] = (bf16)(m - (float)h);
}

// ---------------------------------------------------------------------------
// Kernel 4: out_attn = 0.1 * q @ M. XCD-aligned to final_gemm (r10).
// Padded LDS (stride 104 -> conflict-free b128 reads).
// ---------------------------------------------------------------------------
__global__ __launch_bounds__(256) void qm_kernel(
    const bf16* __restrict__ q_sp, const bf16* __restrict__ M_hi,
    const bf16* __restrict__ M_lo, bf16* __restrict__ out_attn)
{
    const int bid  = blockIdx.y * 256 + blockIdx.x;   // grid (256, 4)
    const int xcd  = bid & 7;
    const int r    = bid >> 3;                        // 0..127
    const int mb   = xcd * 16 + (r & 15);             // final's m-block index
    const int h    = r >> 4;                          // 0..7
    const int tb   = mb >> 2;
    const int cbk  = mb & 3;
    const int g    = tb * HL_ + (h >> 2);
    const int wave = threadIdx.x >> 6;
    const int lane = threadIdx.x & 63;
    const int m16  = lane & 15, quad = lane >> 4;
    const int cw   = cbk * 128 + wave * 32;

    __shared__ __align__(16) bf16 Mh[96 * 104];
    __shared__ __align__(16) bf16 Ml[96 * 104];
    {   // stage M: 96 rows x 12 segs = 1152 chunks per array
        const bf16* gh = M_hi + (size_t)g * HD_ * HD_;
        const bf16* gl = M_lo + (size_t)g * HD_ * HD_;
        #pragma unroll
        for (int j = 0; j < 5; j++) {
            int ci = j * 256 + threadIdx.x;
            if (ci < 1152) {
                int row = ci / 12, seg = ci % 12;
                *(bf16x8*)&Mh[row * 104 + seg * 8] = *(const bf16x8*)(gh + row * HD_ + seg * 8);
                *(bf16x8*)&Ml[row * 104 + seg * 8] = *(const bf16x8*)(gl + row * HD_ + seg * 8);
            }
        }
    }
    __syncthreads();

    f32x4 acc[2][6];
    #pragma unroll
    for (int mi = 0; mi < 2; mi++)
        #pragma unroll
        for (int nt = 0; nt < 6; nt++) { f32x4 z = {0.f,0.f,0.f,0.f}; acc[mi][nt] = z; }

    #pragma unroll
    for (int ks = 0; ks < 3; ++ks) {
        bf16x8 a[2];
        #pragma unroll
        for (int mi = 0; mi < 2; mi++)
            a[mi] = *(const bf16x8*)(q_sp + ((size_t)(tb * C_ + cw + mi * 16 + m16)) * D_
                                     + h * HD_ + ks * 32 + quad * 8);
        #pragma unroll
        for (int nt = 0; nt < 6; ++nt) {
            bf16x8 bh = *(const bf16x8*)&Mh[(nt * 16 + m16) * 104 + ks * 32 + quad * 8];
            bf16x8 bl = *(const bf16x8*)&Ml[(nt * 16 + m16) * 104 + ks * 32 + quad * 8];
            #pragma unroll
            for (int mi = 0; mi < 2; mi++) {
                acc[mi][nt] = __builtin_amdgcn_mfma_f32_16x16x32_bf16(a[mi], bh, acc[mi][nt], 0, 0, 0);
                acc[mi][nt] = __builtin_amdgcn_mfma_f32_16x16x32_bf16(a[mi], bl, acc[mi][nt], 0, 0, 0);
            }
        }
    }
    #pragma unroll
    for (int mi = 0; mi < 2; mi++)
        #pragma unroll
        for (int nt = 0; nt < 6; nt++)
            #pragma unroll
            for (int rr = 0; rr < 4; rr++) {
                int c = cw + mi * 16 + quad * 4 + rr;
                int j = nt * 16 + m16;
                out_attn[((size_t)(tb * C_ + c)) * D_ + h * HD_ + j] = (bf16)(0.1f * acc[mi][nt][rr]);
            }
}

// ---------------------------------------------------------------------------
// Kernel 5: final = out_attn @ wo^T. r10 schedule EXACT (pipelined, XCD
// swizzle) but MFMA 16x16x32 -> 32x32x16: 8 MFMAs/step vs 16, same
// ds_read/staging schedule. Wave tile 64x64 = 2x2 of 32x32.
// ---------------------------------------------------------------------------
__global__ __launch_bounds__(256, 3) void final_gemm_kernel(
    const bf16* __restrict__ A, const bf16* __restrict__ W, float* __restrict__ out)
{
    __shared__ __align__(16) bf16 FA0[128 * 32];   // 8 KB
    __shared__ __align__(16) bf16 FA1[128 * 32];   // 8 KB
    __shared__ __align__(16) bf16 FB0[128 * 32];   // 8 KB
    __shared__ __align__(16) bf16 FB1[128 * 32];   // 8 KB  (32 KB total)

    const int tid  = threadIdx.x;
    const int wave = tid >> 6, lane = tid & 63;
    const int l31  = lane & 31, lo8 = lane >> 5;
    const int wm   = wave >> 1, wn = wave & 1;

    const int bid   = blockIdx.x;                  // grid (768)
    const int xcd   = bid & 7;
    const int local = bid >> 3;                    // 0..95
    const int m0    = ((xcd << 4) | (local & 15)) * 128;   // 128 m-blocks
    const int n0    = (local >> 4) * 128;                  // 6 n-blocks

    f32x16 acc[2][2];
    #pragma unroll
    for (int p = 0; p < 2; p++)
        #pragma unroll
        for (int q = 0; q < 2; q++)
            #pragma unroll
            for (int e = 0; e < 16; e++) acc[p][q][e] = 0.f;

    // staging: 512 chunks/array, 2 per thread. row = ci>>2, slot = ci&3,
    // seg = slot ^ ((row>>1)&3)
    const int c0_ = tid,        r0_ = c0_ >> 2, g0_ = (c0_ & 3) ^ ((c0_ >> 3) & 3);
    const int c1_ = 256 + tid,  r1_ = c1_ >> 2, g1_ = (c1_ & 3) ^ ((c1_ >> 3) & 3);

#define FSTG(Ab, Bb, k0) do {                                                 \
    gld16(A + (size_t)(m0 + r0_) * D_ + (k0) + g0_ * 8, &Ab[c0_ * 8]);        \
    gld16(A + (size_t)(m0 + r1_) * D_ + (k0) + g1_ * 8, &Ab[c1_ * 8]);        \
    gld16(W + (size_t)(n0 + r0_) * D_ + (k0) + g0_ * 8, &Bb[c0_ * 8]);        \
    gld16(W + (size_t)(n0 + r1_) * D_ + (k0) + g1_ * 8, &Bb[c1_ * 8]);        \
} while (0)

    bf16x8 fa[2][2], fb[2][2];

#define FLOAD(Ab, Bb) do {                                                    \
    _Pragma("unroll")                                                         \
    for (int mi = 0; mi < 2; mi++) {                                          \
        int row = wm * 64 + mi * 32 + l31;                                    \
        _Pragma("unroll")                                                     \
        for (int kh = 0; kh < 2; kh++) {                                      \
            int off = row * 32 + ((((kh << 1) | lo8) ^ ((row >> 1) & 3)) * 8);\
            fa[mi][kh] = *(const bf16x8*)&Ab[off];                            \
        }                                                                     \
    }                                                                         \
    _Pragma("unroll")                                                         \
    for (int ni = 0; ni < 2; ni++) {                                          \
        int row = wn * 64 + ni * 32 + l31;                                    \
        _Pragma("unroll")                                                     \
        for (int kh = 0; kh < 2; kh++) {                                      \
            int off = row * 32 + ((((kh << 1) | lo8) ^ ((row >> 1) & 3)) * 8);\
            fb[ni][kh] = *(const bf16x8*)&Bb[off];                            \
        }                                                                     \
    }                                                                         \
} while (0)

#define FMFMA() do {                                                          \
    __builtin_amdgcn_s_setprio(1);                                            \
    _Pragma("unroll")                                                         \
    for (int kh = 0; kh < 2; kh++)                                            \
        _Pragma("unroll")                                                     \
        for (int mi = 0; mi < 2; mi++)                                        \
            _Pragma("unroll")                                                 \
            for (int ni = 0; ni < 2; ni++)                                    \
                acc[mi][ni] = __builtin_amdgcn_mfma_f32_32x32x16_bf16(        \
                    fa[mi][kh], fb[ni][kh], acc[mi][ni], 0, 0, 0);            \
    __builtin_amdgcn_s_setprio(0);                                            \
} while (0)

    FSTG(FA0, FB0, 0);
    FSTG(FA1, FB1, 32);
    NEXT_READY(4);                       // buf0 ready, buf1 in flight

    for (int s = 0; s < 22; s += 2) {    // 24 K-steps total
        FLOAD(FA0, FB0);
        READS_DONE();
        FSTG(FA0, FB0, (s + 2) * 32);
        FMFMA();
        NEXT_READY(4);

        FLOAD(FA1, FB1);
        READS_DONE();
        FSTG(FA1, FB1, (s + 3) * 32);
        FMFMA();
        NEXT_READY(4);
    }
    FLOAD(FA0, FB0);
    READS_DONE();
    FMFMA();
    NEXT_READY(0);
    FLOAD(FA1, FB1);
    FMFMA();

#undef FSTG
#undef FLOAD
#undef FMFMA

    // C/D map: col = l31 (within 32-tile), row = (reg&3)+8*(reg>>2)+4*lo8
    #pragma unroll
    for (int mi = 0; mi < 2; mi++)
        #pragma unroll
        for (int ni = 0; ni < 2; ni++)
            #pragma unroll
            for (int reg = 0; reg < 16; reg++) {
                int row = m0 + wm * 64 + mi * 32 + (reg & 3) + 8 * (reg >> 2) + 4 * lo8;
                int col = n0 + wn * 64 + ni * 32 + l31;
                out[(size_t)row * D_ + col] = acc[mi][ni][reg];
            }
}

// ---------------------------------------------------------------------------
extern "C" void kernel_launch(void* const* d_in, const int* in_sizes, int n_in,
                              void* d_out, int out_size, void* d_ws, size_t ws_size,
                              hipStream_t stream) {
    const float* x    = (const float*)d_in[0];
    const float* q_w  = (const float*)d_in[1];
    const float* k_w  = (const float*)d_in[2];
    const float* v_w  = (const float*)d_in[3];
    const float* wo_w = (const float*)d_in[4];
    float* out = (float*)d_out;

    char* ws = (char*)d_ws;
    bf16* xs    = (bf16*)(ws);                  // 25,165,824  (T,M2,768)
    bf16* q_sp  = (bf16*)(ws + 25165824);       // 25,165,824  (T,M2,768)
    bf16* k_sp  = (bf16*)(ws + 50331648);       //  6,291,456  (T,M2,192)
    bf16* v_sp  = (bf16*)(ws + 56623104);       //  6,291,456  (T,M2,192)
    bf16* whi   = (bf16*)(ws + 62914560);       //  1,769,472  (1152,768)
    bf16* wlo   = (bf16*)(ws + 64684032);       //  1,769,472
    bf16* wo_bf = (bf16*)(ws + 66453504);       //  1,179,648
    bf16* M_hi  = (bf16*)(ws + 67633152);       //  1,179,648  (64,96,96)
    bf16* M_lo  = (bf16*)(ws + 68812800);       //  1,179,648
    unsigned* susp = (unsigned*)(ws + 69992448);//    262,148  (count + entries)
    bf16* out_attn = xs;                        // alias: xs dead after fixup
    float* M_part  = out;                       // d_out as scratch (9.4 MB of 50 MB)

    hipLaunchKernelGGL(prep_kernel, dim3(1536), dim3(256), 0, stream,
                       x, q_w, k_w, v_w, wo_w, xs, whi, wlo, wo_bf, susp);
    hipLaunchKernelGGL(proj_lif_kernel, dim3(M2_ / 64, NCOMB / 64), dim3(256), 0, stream,
                       xs, whi, wlo, q_sp, k_sp, v_sp, susp);
    hipLaunchKernelGGL(fixup_kernel, dim3(1024), dim3(256), 0, stream,
                       xs, q_w, k_w, v_w, q_sp, k_sp, v_sp, susp);
    hipLaunchKernelGGL(ktv_kernel, dim3(T_ * B_ * HL_, 4), dim3(256), 0, stream,
                       k_sp, v_sp, M_part);
    hipLaunchKernelGGL(cvtM_kernel, dim3((64 * HD_ * HD_ + 255) / 256), dim3(256), 0, stream,
                       M_part, M_hi, M_lo);
    hipLaunchKernelGGL(qm_kernel, dim3(256, 4), dim3(256), 0, stream,
                       q_sp, M_hi, M_lo, out_attn);
    hipLaunchKernelGGL(final_gemm_kernel, dim3(768), dim3(256), 0, stream,
                       out_attn, wo_bf, out);
}

// Round 13
// 227.663 us; speedup vs baseline: 1.0187x; 1.0187x over previous
//
#include <hip/hip_runtime.h>

typedef __bf16 bf16;
typedef __bf16 bf16x4 __attribute__((ext_vector_type(4)));
typedef __bf16 bf16x8 __attribute__((ext_vector_type(8)));
typedef float f32x4 __attribute__((ext_vector_type(4)));

#define T_ 4
#define B_ 8
#define C_ 512
#define D_ 768
#define H_ 8
#define HL_ 2
#define HD_ 96
#define MKV_ 192
#define M2_ 4096            // B*C
#define BCD_ 3145728        // B*C*D
#define M3_ 16384           // T*B*C
#define NCOMB 1152          // q(768) + k(192) + v(192)
#define SUSP_CAP 65536
#define SUSP_WIN 2e-4f

// async global->LDS, 16B per lane (dest = wave-uniform base + lane*16; no pad)
__device__ __forceinline__ void gld16(const bf16* g, bf16* l) {
    __builtin_amdgcn_global_load_lds(
        (const __attribute__((address_space(1))) unsigned int*)g,
        (__attribute__((address_space(3))) unsigned int*)l, 16, 0, 0);
}

// all waves finished reading the LDS buffer we are about to overwrite
#define READS_DONE() do {                                                     \
    asm volatile("s_waitcnt lgkmcnt(0)" ::: "memory");                        \
    __builtin_amdgcn_s_barrier();                                             \
    __builtin_amdgcn_sched_barrier(0);                                        \
} while (0)

// counted wait: next buffer's loads (issued a full iter ago) have landed;
// the just-issued ones stay in flight
#define NEXT_READY(N) do {                                                    \
    asm volatile("s_waitcnt vmcnt(" #N ")" ::: "memory");                     \
    __builtin_amdgcn_s_barrier();                                             \
} while (0)

// ---------------------------------------------------------------------------
// Kernel 1: fused prep — VECTORIZED. xs=lif(x) fp64 scan (8/thread,
// float4 loads + bf16x8 stores), q/k/v hi/lo split, wo cvt, susp reset.
// ---------------------------------------------------------------------------
__global__ __launch_bounds__(256) void prep_kernel(
    const float* __restrict__ x, const float* __restrict__ q_w,
    const float* __restrict__ k_w, const float* __restrict__ v_w,
    const float* __restrict__ wo_w, bf16* __restrict__ xs,
    bf16* __restrict__ whi, bf16* __restrict__ wlo, bf16* __restrict__ wo_bf,
    unsigned* __restrict__ susp)
{
    const int t0 = blockIdx.x * 256 + threadIdx.x;
    const int stride = gridDim.x * 256;
    if (t0 == 0) susp[0] = 0;
    for (int i = t0 * 8; i < BCD_; i += stride * 8) {
        double v[8] = {0.0, 0.0, 0.0, 0.0, 0.0, 0.0, 0.0, 0.0};
        #pragma unroll
        for (int t = 0; t < T_; ++t) {
            const float* xp = x + (size_t)t * BCD_ + i;
            f32x4 xa = *(const f32x4*)xp;
            f32x4 xb = *(const f32x4*)(xp + 4);
            bf16x8 s;
            #pragma unroll
            for (int e = 0; e < 8; ++e) {
                float xe = (e < 4) ? xa[e] : xb[e - 4];
                v[e] = v[e] * 0.5 + (double)xe;
                float sp = (v[e] >= 1.0) ? 1.f : 0.f;
                s[e] = (bf16)sp;
                v[e] *= (double)(1.f - sp);     // exact: *0 or *1
            }
            *(bf16x8*)(xs + (size_t)t * BCD_ + i) = s;
        }
    }
    for (int i = t0 * 4; i < NCOMB * D_; i += stride * 4) {
        int row = i / D_, col = i - row * D_;
        const float* src;
        if (row < 768)      src = q_w + (size_t)row * D_ + col;
        else if (row < 960) src = k_w + (size_t)(row - 768) * D_ + col;
        else                src = v_w + (size_t)(row - 960) * D_ + col;
        f32x4 wv = *(const f32x4*)src;
        bf16x4 hh, ll;
        #pragma unroll
        for (int e = 0; e < 4; ++e) {
            bf16 h = (bf16)wv[e];
            hh[e] = h;
            ll[e] = (bf16)(wv[e] - (float)h);
        }
        *(bf16x4*)(whi + i) = hh;
        *(bf16x4*)(wlo + i) = ll;
    }
    for (int i = t0 * 4; i < D_ * D_; i += stride * 4) {
        f32x4 wv = *(const f32x4*)(wo_w + i);
        bf16x4 c;
        #pragma unroll
        for (int e = 0; e < 4; ++e) c[e] = (bf16)wv[e];
        *(bf16x4*)(wo_bf + i) = c;
    }
}

// ---------------------------------------------------------------------------
// Kernel 2: combined spiking projection (r10-EXACT: 64x64 block, BK=32,
// 16x16x32 MFMA, named dbuf 48KB -> 3 blocks/CU, counted-vmcnt prefetch,
// 4-slot XOR swizzle, XCD swizzle). Verified 69.4-70.5us / MfmaUtil 33 /
// 0 bank conflicts across three independent runs.
// ---------------------------------------------------------------------------
__global__ __launch_bounds__(256, 3) void proj_lif_kernel(
    const bf16* __restrict__ xs, const bf16* __restrict__ Whi,
    const bf16* __restrict__ Wlo,
    bf16* __restrict__ q_sp, bf16* __restrict__ k_sp, bf16* __restrict__ v_sp,
    unsigned* __restrict__ susp)
{
    __shared__ __align__(16) bf16 A0[T_][64 * 32];   // 16 KB
    __shared__ __align__(16) bf16 A1[T_][64 * 32];   // 16 KB
    __shared__ __align__(16) bf16 H0[64 * 32];       //  4 KB
    __shared__ __align__(16) bf16 H1[64 * 32];       //  4 KB
    __shared__ __align__(16) bf16 L0[64 * 32];       //  4 KB
    __shared__ __align__(16) bf16 L1[64 * 32];       //  4 KB  (48 KB total)

    const int tid  = threadIdx.x;
    const int wave = tid >> 6, lane = tid & 63;
    const int m16  = lane & 15, quad = lane >> 4;
    const int wm   = wave >> 1, wn = wave & 1;

    // bijective XCD swizzle: xcd = bid&7 gets m-tiles [xcd*8, xcd*8+8) x all n
    const int bid   = blockIdx.y * 64 + blockIdx.x;   // grid (64, 18)
    const int xcd   = bid & 7;
    const int local = bid >> 3;                        // 0..143
    const int m0    = ((xcd << 3) | (local & 7)) * 64; // over M2
    const int n0    = (local >> 3) * 64;               // over NCOMB

    // output section for this wave's 32 columns
    const int colb = n0 + wn * 32;
    bf16* outp; int Nloc, cb;
    if (colb < 768)      { outp = q_sp; Nloc = 768; cb = colb; }
    else if (colb < 960) { outp = k_sp; Nloc = 192; cb = colb - 768; }
    else                 { outp = v_sp; Nloc = 192; cb = colb - 960; }

    f32x4 acc[T_][2][2];
    #pragma unroll
    for (int t = 0; t < T_; t++)
        #pragma unroll
        for (int a = 0; a < 2; a++)
            #pragma unroll
            for (int b = 0; b < 2; b++) { f32x4 z = {0.f,0.f,0.f,0.f}; acc[t][a][b] = z; }

    // staging geometry: chunk = tid -> row = tid>>2, slot = tid&3,
    // source seg = slot ^ ((row>>1)&3)  (inverse swizzle on global src)
    const int srow = tid >> 2;
    const int sseg = (tid & 3) ^ ((tid >> 3) & 3);

#define STAGE(Ab, Hb, Lb, k0) do {                                            \
    _Pragma("unroll")                                                         \
    for (int t = 0; t < T_; t++)                                              \
        gld16(xs + (size_t)(t * M2_ + m0 + srow) * D_ + (k0) + sseg * 8,      \
              &Ab[t][tid * 8]);                                               \
    gld16(Whi + (size_t)(n0 + srow) * D_ + (k0) + sseg * 8, &Hb[tid * 8]);    \
    gld16(Wlo + (size_t)(n0 + srow) * D_ + (k0) + sseg * 8, &Lb[tid * 8]);    \
} while (0)

    bf16x8 a[T_][2], bh[2], bl[2];

#define LOADREGS(Ab, Hb, Lb) do {                                             \
    _Pragma("unroll")                                                         \
    for (int mi = 0; mi < 2; mi++) {                                          \
        int row = wm * 32 + mi * 16 + m16;                                    \
        int off = row * 32 + ((quad ^ ((row >> 1) & 3)) * 8);                 \
        _Pragma("unroll")                                                     \
        for (int t = 0; t < T_; t++) a[t][mi] = *(const bf16x8*)&Ab[t][off];  \
    }                                                                         \
    _Pragma("unroll")                                                         \
    for (int ni = 0; ni < 2; ni++) {                                          \
        int row = wn * 32 + ni * 16 + m16;                                    \
        int off = row * 32 + ((quad ^ ((row >> 1) & 3)) * 8);                 \
        bh[ni] = *(const bf16x8*)&Hb[off];                                    \
        bl[ni] = *(const bf16x8*)&Lb[off];                                    \
    }                                                                         \
} while (0)

#define DOMFMA() do {                                                         \
    __builtin_amdgcn_s_setprio(1);                                            \
    _Pragma("unroll")                                                         \
    for (int ni = 0; ni < 2; ni++)                                            \
        _Pragma("unroll")                                                     \
        for (int t = 0; t < T_; t++)                                          \
            _Pragma("unroll")                                                 \
            for (int mi = 0; mi < 2; mi++) {                                  \
                acc[t][mi][ni] = __builtin_amdgcn_mfma_f32_16x16x32_bf16(     \
                    a[t][mi], bh[ni], acc[t][mi][ni], 0, 0, 0);               \
                acc[t][mi][ni] = __builtin_amdgcn_mfma_f32_16x16x32_bf16(     \
                    a[t][mi], bl[ni], acc[t][mi][ni], 0, 0, 0);               \
            }                                                                 \
    __builtin_amdgcn_s_setprio(0);                                            \
} while (0)

    STAGE(A0, H0, L0, 0);
    STAGE(A1, H1, L1, 32);
    NEXT_READY(6);                       // buf0 ready, buf1 in flight

    for (int s = 0; s < 22; s += 2) {    // iters u = s (buf0), u = s+1 (buf1)
        LOADREGS(A0, H0, L0);
        READS_DONE();
        STAGE(A0, H0, L0, (s + 2) * 32);
        DOMFMA();
        NEXT_READY(6);                   // buf1 (tile s+1) ready

        LOADREGS(A1, H1, L1);
        READS_DONE();
        STAGE(A1, H1, L1, (s + 3) * 32);
        DOMFMA();
        NEXT_READY(6);                   // buf0 (tile s+2) ready
    }
    // iter 22 (buf0): no more staging
    LOADREGS(A0, H0, L0);
    READS_DONE();
    DOMFMA();
    NEXT_READY(0);                       // buf1 (tile 23) ready
    // iter 23 (buf1)
    LOADREGS(A1, H1, L1);
    DOMFMA();

#undef STAGE
#undef LOADREGS
#undef DOMFMA

    // LIF scan over t (registers only) + spike stores + suspect flags
    #pragma unroll
    for (int mi = 0; mi < 2; mi++)
        #pragma unroll
        for (int ni = 0; ni < 2; ni++)
            #pragma unroll
            for (int rr = 0; rr < 4; rr++) {
                int row = m0 + wm * 32 + mi * 16 + quad * 4 + rr;
                int lc  = cb + ni * 16 + m16;
                float v = 0.f;
                bool suspect = false;
                #pragma unroll
                for (int t = 0; t < T_; t++) {
                    v = v * 0.5f + acc[t][mi][ni][rr];
                    float d = v - 1.0f;
                    if (fabsf(d) < SUSP_WIN) suspect = true;
                    float sp = (d >= 0.f) ? 1.f : 0.f;
                    v *= (1.f - sp);
                    outp[(size_t)(t * M2_ + row) * Nloc + lc] = (bf16)sp;
                }
                if (suspect) {
                    int ccol = n0 + wn * 32 + ni * 16 + m16;
                    unsigned idx = atomicAdd(susp, 1u);
                    if (idx < SUSP_CAP) susp[1 + idx] = (unsigned)(row * 2048 + ccol);
                }
            }
}

// ---------------------------------------------------------------------------
// Kernel 2b: fp64 fixup, LATENCY-FLAT: prefetch the full W row (12 f32/lane)
// and all 4 xs rows (48 bf16/lane) as independent loads -> ONE memory wait
// -> 4 in-register dots + shuffle reduce + scan. Grid 1024.
// ---------------------------------------------------------------------------
__global__ __launch_bounds__(256) void fixup_kernel(
    const bf16* __restrict__ xs, const float* __restrict__ q_w,
    const float* __restrict__ k_w, const float* __restrict__ v_w,
    bf16* __restrict__ q_sp, bf16* __restrict__ k_sp, bf16* __restrict__ v_sp,
    const unsigned* __restrict__ susp)
{
    unsigned count = susp[0];
    if (count > SUSP_CAP) count = SUSP_CAP;
    const int lane = threadIdx.x & 63;
    const int wid  = (blockIdx.x * blockDim.x + threadIdx.x) >> 6;
    const int nw   = (gridDim.x * blockDim.x) >> 6;
    for (unsigned i = wid; i < count; i += nw) {
        unsigned e = susp[1 + i];
        int row = e >> 11, col = e & 2047;
        const float* W; bf16* outp; int Nloc, lc;
        if (col < 768)      { W = q_w + (size_t)col * D_;         outp = q_sp; Nloc = 768; lc = col; }
        else if (col < 960) { W = k_w + (size_t)(col - 768) * D_; outp = k_sp; Nloc = 192; lc = col - 768; }
        else                { W = v_w + (size_t)(col - 960) * D_; outp = v_sp; Nloc = 192; lc = col - 960; }
        float w[12];
        #pragma unroll
        for (int j = 0; j < 12; ++j) w[j] = W[lane + j * 64];
        float av[T_][12];
        #pragma unroll
        for (int t = 0; t < T_; ++t) {
            const bf16* ar = xs + (size_t)(t * M2_ + row) * D_;
            #pragma unroll
            for (int j = 0; j < 12; ++j) av[t][j] = (float)ar[lane + j * 64];
        }
        double v = 0.0;
        #pragma unroll
        for (int t = 0; t < T_; ++t) {
            double y = 0.0;
            #pragma unroll
            for (int j = 0; j < 12; ++j)
                y += (double)av[t][j] * (double)w[j];
            #pragma unroll
            for (int off = 1; off < 64; off <<= 1)
                y += __shfl_xor(y, off);
            v = v * 0.5 + y;
            unsigned sp = (v >= 1.0) ? 1u : 0u;
            if (lane == 0) outp[(size_t)(t * M2_ + row) * Nloc + lc] = (bf16)(float)sp;
            if (sp) v = 0.0;
        }
    }
}

// ---------------------------------------------------------------------------
// Kernel 3: partial k^T v. Block (g, cc): c-range cc*128..+128 (4 slices ->
// 256 blocks). Vectorized bf16x8 global loads, scalar LDS transpose
// scatter. fp32 exact integer partials -> M_part[cc][g][96][96].
// ---------------------------------------------------------------------------
__global__ __launch_bounds__(256) void ktv_kernel(
    const bf16* __restrict__ k_sp, const bf16* __restrict__ v_sp,
    float* __restrict__ M_part)
{
    const int g    = blockIdx.x;
    const int cc   = blockIdx.y;
    const int kvh  = g % HL_;
    const int tb   = g / HL_;
    const int wave = threadIdx.x >> 6;
    const int lane = threadIdx.x & 63;
    const int m16  = lane & 15, quad = lane >> 4;

    __shared__ __align__(16) bf16 klds[96 * 40];
    __shared__ __align__(16) bf16 vlds[96 * 40];

    f32x4 acc[9];
    #pragma unroll
    for (int i = 0; i < 9; i++) { f32x4 z = {0.f,0.f,0.f,0.f}; acc[i] = z; }

    const bf16* kbase = k_sp + ((size_t)tb * C_ + cc * 128) * MKV_ + kvh * HD_;
    const bf16* vbase = v_sp + ((size_t)tb * C_ + cc * 128) * MKV_ + kvh * HD_;

    for (int c0 = 0; c0 < 128; c0 += 32) {
        __syncthreads();
        // 32c x 12segs x 2 arrays = 768 bf16x8 chunks, 3 per thread
        for (int ci = threadIdx.x; ci < 768; ci += 256) {
            int arr = ci & 1;
            int pos = ci >> 1;
            int c = pos / 12, seg = pos - c * 12;
            const bf16* src = (arr ? vbase : kbase) + (size_t)(c0 + c) * MKV_ + seg * 8;
            bf16x8 val = *(const bf16x8*)src;
            bf16* dst = arr ? vlds : klds;
            #pragma unroll
            for (int e = 0; e < 8; e++)
                dst[(seg * 8 + e) * 40 + c] = val[e];
        }
        __syncthreads();
        #pragma unroll
        for (int i = 0; i < 9; i++) {
            int tile = wave + i * 4;
            int mt = tile / 6, nt = tile % 6;
            bf16x8 a = *(const bf16x8*)(&klds[(mt * 16 + m16) * 40 + quad * 8]);
            bf16x8 b = *(const bf16x8*)(&vlds[(nt * 16 + m16) * 40 + quad * 8]);
            acc[i] = __builtin_amdgcn_mfma_f32_16x16x32_bf16(a, b, acc[i], 0, 0, 0);
        }
    }
    float* op = M_part + ((size_t)cc * 64 + g) * HD_ * HD_;
    #pragma unroll
    for (int i = 0; i < 9; i++) {
        int tile = wave + i * 4;
        int mt = tile / 6, nt = tile % 6;
        #pragma unroll
        for (int r = 0; r < 4; r++) {
            int d = mt * 16 + quad * 4 + r;
            int j = nt * 16 + m16;
            op[(size_t)j * HD_ + d] = acc[i][r];
        }
    }
}

// ---------------------------------------------------------------------------
// Kernel 3b: sum 4 partials, split to exact hi/lo bf16.
// ---------------------------------------------------------------------------
__global__ __launch_bounds__(256) void cvtM_kernel(
    const float* __restrict__ M_part, bf16* __restrict__ M_hi,
    bf16* __restrict__ M_lo)
{
    int i = blockIdx.x * 256 + threadIdx.x;
    if (i >= 64 * HD_ * HD_) return;
    float m = 0.f;
    #pragma unroll
    for (int j = 0; j < 4; j++)
        m += M_part[i + (size_t)j * 589824];
    bf16 h = (bf16)m;
    M_hi[i] = h;
    M_lo[i] = (bf16)(m - (float)h);
}

// ---------------------------------------------------------------------------
// Kernel 4: out_attn = 0.1 * q @ M. XCD-aligned to final_gemm: block
// decodes (mb, h) with mb = xcd*16 + (r&15), matching final's m-block→XCD
// map, so final's A-read hits the producing XCD's L2. 1024 = 8x16x8.
// Padded LDS (stride 104 -> conflict-free b128 reads).
// ---------------------------------------------------------------------------
__global__ __launch_bounds__(256) void qm_kernel(
    const bf16* __restrict__ q_sp, const bf16* __restrict__ M_hi,
    const bf16* __restrict__ M_lo, bf16* __restrict__ out_attn)
{
    const int bid  = blockIdx.y * 256 + blockIdx.x;   // grid (256, 4)
    const int xcd  = bid & 7;
    const int r    = bid >> 3;                        // 0..127
    const int mb   = xcd * 16 + (r & 15);             // final's m-block index
    const int h    = r >> 4;                          // 0..7
    const int tb   = mb >> 2;
    const int cbk  = mb & 3;
    const int g    = tb * HL_ + (h >> 2);
    const int wave = threadIdx.x >> 6;
    const int lane = threadIdx.x & 63;
    const int m16  = lane & 15, quad = lane >> 4;
    const int cw   = cbk * 128 + wave * 32;

    __shared__ __align__(16) bf16 Mh[96 * 104];
    __shared__ __align__(16) bf16 Ml[96 * 104];
    {   // stage M: 96 rows x 12 segs = 1152 chunks per array
        const bf16* gh = M_hi + (size_t)g * HD_ * HD_;
        const bf16* gl = M_lo + (size_t)g * HD_ * HD_;
        #pragma unroll
        for (int j = 0; j < 5; j++) {
            int ci = j * 256 + threadIdx.x;
            if (ci < 1152) {
                int row = ci / 12, seg = ci % 12;
                *(bf16x8*)&Mh[row * 104 + seg * 8] = *(const bf16x8*)(gh + row * HD_ + seg * 8);
                *(bf16x8*)&Ml[row * 104 + seg * 8] = *(const bf16x8*)(gl + row * HD_ + seg * 8);
            }
        }
    }
    __syncthreads();

    f32x4 acc[2][6];
    #pragma unroll
    for (int mi = 0; mi < 2; mi++)
        #pragma unroll
        for (int nt = 0; nt < 6; nt++) { f32x4 z = {0.f,0.f,0.f,0.f}; acc[mi][nt] = z; }

    #pragma unroll
    for (int ks = 0; ks < 3; ++ks) {
        bf16x8 a[2];
        #pragma unroll
        for (int mi = 0; mi < 2; mi++)
            a[mi] = *(const bf16x8*)(q_sp + ((size_t)(tb * C_ + cw + mi * 16 + m16)) * D_
                                     + h * HD_ + ks * 32 + quad * 8);
        #pragma unroll
        for (int nt = 0; nt < 6; ++nt) {
            bf16x8 bh = *(const bf16x8*)&Mh[(nt * 16 + m16) * 104 + ks * 32 + quad * 8];
            bf16x8 bl = *(const bf16x8*)&Ml[(nt * 16 + m16) * 104 + ks * 32 + quad * 8];
            #pragma unroll
            for (int mi = 0; mi < 2; mi++) {
                acc[mi][nt] = __builtin_amdgcn_mfma_f32_16x16x32_bf16(a[mi], bh, acc[mi][nt], 0, 0, 0);
                acc[mi][nt] = __builtin_amdgcn_mfma_f32_16x16x32_bf16(a[mi], bl, acc[mi][nt], 0, 0, 0);
            }
        }
    }
    #pragma unroll
    for (int mi = 0; mi < 2; mi++)
        #pragma unroll
        for (int nt = 0; nt < 6; nt++)
            #pragma unroll
            for (int rr = 0; rr < 4; rr++) {
                int c = cw + mi * 16 + quad * 4 + rr;
                int j = nt * 16 + m16;
                out_attn[((size_t)(tb * C_ + c)) * D_ + h * HD_ + j] = (bf16)(0.1f * acc[mi][nt][rr]);
            }
}

// ---------------------------------------------------------------------------
// Kernel 5: final = out_attn @ wo^T (pipelined + XCD swizzle; qm writes A
// rows on the same XCD -> A-read is L2-hot).
// ---------------------------------------------------------------------------
__global__ __launch_bounds__(256, 3) void final_gemm_kernel(
    const bf16* __restrict__ A, const bf16* __restrict__ W, float* __restrict__ out)
{
    __shared__ __align__(16) bf16 FA0[128 * 32];   // 8 KB
    __shared__ __align__(16) bf16 FA1[128 * 32];   // 8 KB
    __shared__ __align__(16) bf16 FB0[128 * 32];   // 8 KB
    __shared__ __align__(16) bf16 FB1[128 * 32];   // 8 KB  (32 KB total)

    const int tid  = threadIdx.x;
    const int wave = tid >> 6, lane = tid & 63;
    const int m16  = lane & 15, quad = lane >> 4;
    const int wm   = wave >> 1, wn = wave & 1;

    const int bid   = blockIdx.x;                  // grid (768)
    const int xcd   = bid & 7;
    const int local = bid >> 3;                    // 0..95
    const int m0    = ((xcd << 4) | (local & 15)) * 128;   // 128 m-blocks
    const int n0    = (local >> 4) * 128;                  // 6 n-blocks

    f32x4 acc[4][4];
    #pragma unroll
    for (int p = 0; p < 4; p++)
        #pragma unroll
        for (int q = 0; q < 4; q++) { f32x4 z = {0.f,0.f,0.f,0.f}; acc[p][q] = z; }

    // staging: 512 chunks/array, 2 per thread. row = ci>>2, slot = ci&3,
    // seg = slot ^ ((row>>1)&3)
    const int c0_ = tid,        r0_ = c0_ >> 2, g0_ = (c0_ & 3) ^ ((c0_ >> 3) & 3);
    const int c1_ = 256 + tid,  r1_ = c1_ >> 2, g1_ = (c1_ & 3) ^ ((c1_ >> 3) & 3);

#define FSTG(Ab, Bb, k0) do {                                                 \
    gld16(A + (size_t)(m0 + r0_) * D_ + (k0) + g0_ * 8, &Ab[c0_ * 8]);        \
    gld16(A + (size_t)(m0 + r1_) * D_ + (k0) + g1_ * 8, &Ab[c1_ * 8]);        \
    gld16(W + (size_t)(n0 + r0_) * D_ + (k0) + g0_ * 8, &Bb[c0_ * 8]);        \
    gld16(W + (size_t)(n0 + r1_) * D_ + (k0) + g1_ * 8, &Bb[c1_ * 8]);        \
} while (0)

    bf16x8 fa[4], fb[4];

#define FLOAD(Ab, Bb) do {                                                    \
    _Pragma("unroll")                                                         \
    for (int mi = 0; mi < 4; mi++) {                                          \
        int row = wm * 64 + mi * 16 + m16;                                    \
        int off = row * 32 + ((quad ^ ((row >> 1) & 3)) * 8);                 \
        fa[mi] = *(const bf16x8*)&Ab[off];                                    \
    }                                                                         \
    _Pragma("unroll")                                                         \
    for (int ni = 0; ni < 4; ni++) {                                          \
        int row = wn * 64 + ni * 16 + m16;                                    \
        int off = row * 32 + ((quad ^ ((row >> 1) & 3)) * 8);                 \
        fb[ni] = *(const bf16x8*)&Bb[off];                                    \
    }                                                                         \
} while (0)

#define FMFMA() do {                                                          \
    __builtin_amdgcn_s_setprio(1);                                            \
    _Pragma("unroll")                                                         \
    for (int mi = 0; mi < 4; mi++)                                            \
        _Pragma("unroll")                                                     \
        for (int ni = 0; ni < 4; ni++)                                        \
            acc[mi][ni] = __builtin_amdgcn_mfma_f32_16x16x32_bf16(            \
                fa[mi], fb[ni], acc[mi][ni], 0, 0, 0);                        \
    __builtin_amdgcn_s_setprio(0);                                            \
} while (0)

    FSTG(FA0, FB0, 0);
    FSTG(FA1, FB1, 32);
    NEXT_READY(4);                       // buf0 ready, buf1 in flight

    for (int s = 0; s < 22; s += 2) {    // 24 K-steps total
        FLOAD(FA0, FB0);
        READS_DONE();
        FSTG(FA0, FB0, (s + 2) * 32);
        FMFMA();
        NEXT_READY(4);

        FLOAD(FA1, FB1);
        READS_DONE();
        FSTG(FA1, FB1, (s + 3) * 32);
        FMFMA();
        NEXT_READY(4);
    }
    FLOAD(FA0, FB0);
    READS_DONE();
    FMFMA();
    NEXT_READY(0);
    FLOAD(FA1, FB1);
    FMFMA();

#undef FSTG
#undef FLOAD
#undef FMFMA

    #pragma unroll
    for (int mi = 0; mi < 4; mi++)
        #pragma unroll
        for (int ni = 0; ni < 4; ni++)
            #pragma unroll
            for (int r = 0; r < 4; r++) {
                int row = m0 + wm * 64 + mi * 16 + quad * 4 + r;
                int col = n0 + wn * 64 + ni * 16 + m16;
                out[(size_t)row * D_ + col] = acc[mi][ni][r];
            }
}

// ---------------------------------------------------------------------------
extern "C" void kernel_launch(void* const* d_in, const int* in_sizes, int n_in,
                              void* d_out, int out_size, void* d_ws, size_t ws_size,
                              hipStream_t stream) {
    const float* x    = (const float*)d_in[0];
    const float* q_w  = (const float*)d_in[1];
    const float* k_w  = (const float*)d_in[2];
    const float* v_w  = (const float*)d_in[3];
    const float* wo_w = (const float*)d_in[4];
    float* out = (float*)d_out;

    char* ws = (char*)d_ws;
    bf16* xs    = (bf16*)(ws);                  // 25,165,824  (T,M2,768)
    bf16* q_sp  = (bf16*)(ws + 25165824);       // 25,165,824  (T,M2,768)
    bf16* k_sp  = (bf16*)(ws + 50331648);       //  6,291,456  (T,M2,192)
    bf16* v_sp  = (bf16*)(ws + 56623104);       //  6,291,456  (T,M2,192)
    bf16* whi   = (bf16*)(ws + 62914560);       //  1,769,472  (1152,768)
    bf16* wlo   = (bf16*)(ws + 64684032);       //  1,769,472
    bf16* wo_bf = (bf16*)(ws + 66453504);       //  1,179,648
    bf16* M_hi  = (bf16*)(ws + 67633152);       //  1,179,648  (64,96,96)
    bf16* M_lo  = (bf16*)(ws + 68812800);       //  1,179,648
    unsigned* susp = (unsigned*)(ws + 69992448);//    262,148  (count + entries)
    bf16* out_attn = xs;                        // alias: xs dead after fixup
    float* M_part  = out;                       // d_out as scratch (9.4 MB of 50 MB)

    hipLaunchKernelGGL(prep_kernel, dim3(1536), dim3(256), 0, stream,
                       x, q_w, k_w, v_w, wo_w, xs, whi, wlo, wo_bf, susp);
    hipLaunchKernelGGL(proj_lif_kernel, dim3(M2_ / 64, NCOMB / 64), dim3(256), 0, stream,
                       xs, whi, wlo, q_sp, k_sp, v_sp, susp);
    hipLaunchKernelGGL(fixup_kernel, dim3(1024), dim3(256), 0, stream,
                       xs, q_w, k_w, v_w, q_sp, k_sp, v_sp, susp);
    hipLaunchKernelGGL(ktv_kernel, dim3(T_ * B_ * HL_, 4), dim3(256), 0, stream,
                       k_sp, v_sp, M_part);
    hipLaunchKernelGGL(cvtM_kernel, dim3((64 * HD_ * HD_ + 255) / 256), dim3(256), 0, stream,
                       M_part, M_hi, M_lo);
    hipLaunchKernelGGL(qm_kernel, dim3(256, 4), dim3(256), 0, stream,
                       q_sp, M_hi, M_lo, out_attn);
    hipLaunchKernelGGL(final_gemm_kernel, dim3(768), dim3(256), 0, stream,
                       out_attn, wo_bf, out);
}